// Round 13
// baseline (620.218 us; speedup 1.0000x reference)
//
#include <hip/hip_runtime.h>
#include <hip/hip_bf16.h>

// FractalTransformer fused kernels, round 13.
// r12's counted-vmcnt single-phase ring REGRESSED (115 vs 98): it removed
// r11's T15 update-overlap; drain savings < overlap loss. Revert to r11's
// proven schedule (T15 2-deep, 1 __syncthreads/tile, LDS k-broadcast,
// M_wave=32, launch_bounds(256,3)) and switch the MFMA shape:
// 16x16x32 -> 32x32x16 (2382 vs 2075 TF ubench, ~+14% rate) with HALF the
// tiles (16 x 32sk) -> half the barriers/phases/instructions at same FLOPs.
// A/B packed symmetrically (lane&31=row|col, lane>>5=k-half for BOTH) so
// any internal k-permutation cancels; C/D layout is the m74/m101-verified
// col=lane&31, row=(reg&3)+8*(reg>>2)+4*(lane>>5).

typedef __attribute__((ext_vector_type(8))) short short8;
typedef __attribute__((ext_vector_type(4))) float f32x4;
typedef __attribute__((ext_vector_type(16))) float f32x16;
typedef __attribute__((ext_vector_type(8))) _Float16 half8;
typedef __attribute__((ext_vector_type(4))) _Float16 half4;

#define DD 256
#define SS 512
#define LOG2E 1.4426950408889634f
#define LN2   0.6931471805599453f

__device__ __forceinline__ unsigned short f2bf(float f) {
  unsigned int b = __float_as_uint(f);
  b += 0x7FFFu + ((b >> 16) & 1u);   // RNE
  return (unsigned short)(b >> 16);
}
__device__ __forceinline__ short8 cvt8(f32x4 lo, f32x4 hi) {
  short8 r;
  r[0]=(short)f2bf(lo[0]); r[1]=(short)f2bf(lo[1]);
  r[2]=(short)f2bf(lo[2]); r[3]=(short)f2bf(lo[3]);
  r[4]=(short)f2bf(hi[0]); r[5]=(short)f2bf(hi[1]);
  r[6]=(short)f2bf(hi[2]); r[7]=(short)f2bf(hi[3]);
  return r;
}
__device__ __forceinline__ void gload16(const void* g, void* l) {
  __builtin_amdgcn_global_load_lds(
      (const __attribute__((address_space(1))) void*)g,
      (__attribute__((address_space(3))) void*)l,
      16, 0, 0);
}

// ------------------------------------------------------------------
// One-time: bf16-convert 6 weights; (w_al + I) -> f16. out = 7 x [256][256].
// ------------------------------------------------------------------
__global__ __launch_bounds__(256) void prep_weights(
    const float* __restrict__ w0, const float* __restrict__ w1,
    const float* __restrict__ w2, const float* __restrict__ w3,
    const float* __restrict__ w4, const float* __restrict__ w5,
    const float* __restrict__ wal, unsigned short* __restrict__ out)
{
  const int bi = blockIdx.x;               // 7*32
  const int m = bi >> 5;
  const int off = ((bi & 31) * 256 + threadIdx.x) * 8;
  const float* src = m==0?w0: m==1?w1: m==2?w2: m==3?w3: m==4?w4: m==5?w5: wal;
  f32x4 a = *(const f32x4*)(src + off);
  f32x4 b = *(const f32x4*)(src + off + 4);
  if (m == 6) {                            // fold residual (+I), store f16
    const int e = off >> 8, d = off & 255;
#pragma unroll
    for (int jj = 0; jj < 4; ++jj) {
      if (e == d + jj)     a[jj] += 1.0f;
      if (e == d + 4 + jj) b[jj] += 1.0f;
    }
    half8 h;
#pragma unroll
    for (int jj = 0; jj < 4; ++jj) {
      h[jj]     = (_Float16)a[jj];
      h[jj + 4] = (_Float16)b[jj];
    }
    *(half8*)(out + (size_t)m * 65536 + off) = h;
  } else {
    *(short8*)(out + (size_t)m * 65536 + off) = cvt8(a, b);
  }
}

// ------------------------------------------------------------------
// out[1024,256] = A @ Wbf^T (+res1)(+res2). grid 256 = 64 rowblk x 4 colblk.
// ------------------------------------------------------------------
__global__ __launch_bounds__(256) void linear_bf(
    const float* __restrict__ A, const unsigned short* __restrict__ Wbf,
    const float* __restrict__ res1, const float* __restrict__ res2,
    float* __restrict__ out)
{
  const int bi = blockIdx.x;
  const int rb = (bi >> 2) * 16;
  const int cb = (bi & 3) * 64;
  const int tid = threadIdx.x;
  const int wv = tid >> 6, lane = tid & 63;
  const int g = lane >> 4, c = lane & 15;
  const int arow = rb + c;
  const int wrow = cb + wv * 16 + c;

  f32x4 acc = (f32x4){0.f, 0.f, 0.f, 0.f};
#pragma unroll
  for (int ks = 0; ks < 8; ++ks) {
    const int d0 = ks * 32 + g * 8;
    f32x4 a0 = *(const f32x4*)(A + arow * DD + d0);
    f32x4 a1 = *(const f32x4*)(A + arow * DD + d0 + 4);
    short8 av = cvt8(a0, a1);
    short8 bv = *(const short8*)(Wbf + wrow * DD + d0);
    acc = __builtin_amdgcn_mfma_f32_16x16x32_bf16(av, bv, acc, 0, 0, 0);
  }
#pragma unroll
  for (int j = 0; j < 4; ++j) {
    const int ro = rb + g * 4 + j;
    const int co = cb + wv * 16 + c;
    float v = acc[j];
    if (res1) v += res1[ro * DD + co];
    if (res2) v += res2[ro * DD + co];
    out[ro * DD + co] = v;
  }
}

// ------------------------------------------------------------------
// q = f16((X + X@Wq^T)*log2e);  k,v = f16(X + X@{Wk,Wv}^T)
// ------------------------------------------------------------------
__global__ __launch_bounds__(256) void linear_qkv(
    const float* __restrict__ X,
    const unsigned short* __restrict__ Wq, const unsigned short* __restrict__ Wk,
    const unsigned short* __restrict__ Wv,
    _Float16* __restrict__ qout, _Float16* __restrict__ kout,
    _Float16* __restrict__ vout)
{
  const int bi = blockIdx.x;
  const int rb = (bi >> 2) * 16;
  const int cb = (bi & 3) * 64;
  const int tid = threadIdx.x;
  const int wv = tid >> 6, lane = tid & 63;
  const int g = lane >> 4, c = lane & 15;
  const int arow = rb + c;
  const int wrow = cb + wv * 16 + c;

  f32x4 aq = (f32x4){0.f,0.f,0.f,0.f};
  f32x4 ak = (f32x4){0.f,0.f,0.f,0.f};
  f32x4 av_ = (f32x4){0.f,0.f,0.f,0.f};
#pragma unroll
  for (int ks = 0; ks < 8; ++ks) {
    const int d0 = ks * 32 + g * 8;
    f32x4 a0 = *(const f32x4*)(X + arow * DD + d0);
    f32x4 a1 = *(const f32x4*)(X + arow * DD + d0 + 4);
    short8 af = cvt8(a0, a1);
    short8 bq = *(const short8*)(Wq + wrow * DD + d0);
    aq = __builtin_amdgcn_mfma_f32_16x16x32_bf16(af, bq, aq, 0, 0, 0);
    short8 bk = *(const short8*)(Wk + wrow * DD + d0);
    ak = __builtin_amdgcn_mfma_f32_16x16x32_bf16(af, bk, ak, 0, 0, 0);
    short8 bv = *(const short8*)(Wv + wrow * DD + d0);
    av_ = __builtin_amdgcn_mfma_f32_16x16x32_bf16(af, bv, av_, 0, 0, 0);
  }
#pragma unroll
  for (int j = 0; j < 4; ++j) {
    const int ro = rb + g * 4 + j;
    const int co = cb + wv * 16 + c;
    const float base = X[ro * DD + co];
    qout[ro * DD + co] = (_Float16)((base + aq[j]) * LOG2E);
    kout[ro * DD + co] = (_Float16)(base + ak[j]);
    vout[ro * DD + co] = (_Float16)(base + av_[j]);
  }
}

// ------------------------------------------------------------------
// Pack k,v (f16, [b][s][d]) into 32x32x16 fragment order.
// k (ids 0..32767): id = b*16384 + t*1024 + ks*64 + lane -> 8 f16:
//   k[b][t*32 + (lane&31)][ks*16 + (lane>>5)*8 + 0..7]
// v (ids 32768..65535): id2 = b*16384 + t*1024 + slice*128 + lane*2 + g2
//   -> 8 f16: v[b][t*32 + (lane&31)][eb + {0..3, 8..11}],
//   eb = slice*32 + 4*(lane>>5) + 16*g2
// ------------------------------------------------------------------
__global__ __launch_bounds__(256) void pack_kv(
    const _Float16* __restrict__ k, const _Float16* __restrict__ v,
    _Float16* __restrict__ kfrag, _Float16* __restrict__ vfrag)
{
  const int id = blockIdx.x * 256 + threadIdx.x;   // 65536
  if (id < 32768) {
    const int lane = id & 63, ks = (id >> 6) & 15, t = (id >> 10) & 15, b = id >> 14;
    const _Float16* src = k + ((size_t)(b * SS + t * 32 + (lane & 31)) * DD
                               + ks * 16 + (lane >> 5) * 8);
    *(half8*)(kfrag + (size_t)id * 8) = *(const half8*)src;
  } else {
    const int id2 = id - 32768;                    // 0..32767
    const int g2 = id2 & 1, lane = (id2 >> 1) & 63, slice = (id2 >> 7) & 7,
              t = (id2 >> 10) & 15, b = id2 >> 14;
    const int row = b * SS + t * 32 + (lane & 31);
    const int eb = slice * 32 + 4 * (lane >> 5) + 16 * g2;
    half4 lo = *(const half4*)(v + (size_t)row * DD + eb);
    half4 hi = *(const half4*)(v + (size_t)row * DD + eb + 8);
    half8 h;
#pragma unroll
    for (int j = 0; j < 4; ++j) { h[j] = lo[j]; h[j + 4] = hi[j]; }
    *(half8*)(vfrag + (size_t)id2 * 8) = h;
  }
}

// ------------------------------------------------------------------
// Fused fractal attention v13. Grid 2048 = b x sq x eh; 4 waves (256 thr).
// slice = eh*4+wv owns e in [slice*32, +32). 16 tiles of 32 sk;
// mfma_f32_32x32x16_f16 (16 MFMAs/tile). k tiles (16KB fragment-linear)
// LDS double-buffered via straight gload_lds; T15 accA/accB pipeline;
// 1 __syncthreads per tile (r11's proven schedule).
// ------------------------------------------------------------------
__global__ __launch_bounds__(256, 3) void fractal_attn(
    const _Float16* __restrict__ walI,   // f16 (wal+I), [256][256]
    const _Float16* __restrict__ qf,     // f16, pre-scaled by log2e
    const _Float16* __restrict__ kfrag,  // f16 fragment-packed (32x32x16)
    const _Float16* __restrict__ vfrag,  // f16 fragment-packed (slice-32)
    float* __restrict__ vsum)
{
  __shared__ _Float16 kt[2][8192];       // 2 x 16KB k tiles

  const int bid = blockIdx.x;            // 2048
  const int eh = bid & 1;
  const int sq = (bid >> 1) & 511;
  const int b  = bid >> 10;
  const int tid = threadIdx.x;
  const int wv = tid >> 6;
  const int lane = tid & 63;
  const int l31 = lane & 31, kh = lane >> 5;
  const int slice = eh * 4 + wv;
  const int sbase = slice * 32;

  // ---- k tile staging: straight linear copy, 256 thr x 4 x 16B = 16KB ----
  const _Float16* ktile0 = kfrag + (size_t)b * 131072;   // + t*8192 halfs
  auto stage = [&](int t) {
    const _Float16* src = ktile0 + (size_t)t * 8192;
    _Float16* dst = &kt[t & 1][0];
#pragma unroll
    for (int it = 0; it < 4; ++it)
      gload16(src + it * 2048 + tid * 8, dst + it * 2048 + tid * 8);
  };

  stage(0);   // completes while we build A'

  // ---- A' fragments: lane holds e = sbase + l31, k-half kh ----
  half8 afrag[16];
  {
    const _Float16* qrow = qf + (size_t)(b * SS + sq) * DD;
    const _Float16* wrow = walI + (size_t)(sbase + l31) * DD;
#pragma unroll
    for (int ks = 0; ks < 16; ++ks) {
      half8 q8 = *(const half8*)(qrow + ks * 16 + kh * 8);
      half8 w8 = *(const half8*)(wrow + ks * 16 + kh * 8);
      afrag[ks] = w8 * q8;
    }
  }

  // ---- v fragment base: half off = b*131072 + t*8192 + slice*1024 + lane*16
  const _Float16* vfb = vfrag + (size_t)b * 131072 + slice * 1024 + lane * 16;

  // ---- state: 16 e-slots per lane; e = sbase+(s&3)+8*(s>>2)+4*kh ----
  float mst[16], sst[16], vst[16];
#pragma unroll
  for (int s = 0; s < 16; ++s) { mst[s] = -1e30f; sst[s] = 0.f; vst[s] = 0.f; }

  f32x16 accA, accB;
  half8 vqaA, vqbA, vqaB, vqbB;
  const f32x16 zeroc = (f32x16)(0.f);

#define LOADV(T, A_, B_)                                            \
  {                                                                 \
    const _Float16* vf_ = vfb + (size_t)(T) * 8192;                 \
    A_ = *(const half8*)(vf_);                                      \
    B_ = *(const half8*)(vf_ + 8);                                  \
  }
#define MFMA_INTO(ACC, T)                                           \
  {                                                                 \
    const _Float16* kb_ = &kt[(T) & 1][0];                          \
    __builtin_amdgcn_s_setprio(1);                                  \
    {                                                               \
      half8 bf0 = *(const half8*)(kb_ + lane * 8);                  \
      ACC = __builtin_amdgcn_mfma_f32_32x32x16_f16(                 \
          afrag[0], bf0, zeroc, 0, 0, 0);                           \
    }                                                               \
    _Pragma("unroll")                                               \
    for (int ks = 1; ks < 16; ++ks) {                               \
      half8 bf_ = *(const half8*)(kb_ + ks * 512 + lane * 8);       \
      ACC = __builtin_amdgcn_mfma_f32_32x32x16_f16(                 \
          afrag[ks], bf_, ACC, 0, 0, 0);                            \
    }                                                               \
    __builtin_amdgcn_s_setprio(0);                                  \
  }
#define UPDATE(ACC, VA, VB)                                         \
  {                                                                 \
    _Pragma("unroll")                                               \
    for (int s = 0; s < 16; ++s) {                                  \
      const float L = ACC[s];                                       \
      mst[s] = fmaxf(mst[s], L);                                    \
      const float p = L * __builtin_amdgcn_exp2f(L);                \
      sst[s] += fabsf(p);                                           \
      const float vv = (s < 8) ? (float)VA[s] : (float)VB[s - 8];   \
      vst[s] = fmaf(vv, p, vst[s]);                                 \
    }                                                               \
  }

  // ---- prologue ----
  LOADV(0, vqaA, vqbA);
  __syncthreads();            // stage(0) complete
  stage(1);
  MFMA_INTO(accA, 0);         // tile 0

#pragma unroll 1
  for (int t = 1; t < 15; t += 2) {
    __syncthreads();          // stage(t) complete; buf[(t+1)&1] free
    LOADV(t, vqaB, vqbB);
    stage(t + 1);
    MFMA_INTO(accB, t);       // tile t
    UPDATE(accA, vqaA, vqbA); // tile t-1 (overlaps MFMA pipe)

    __syncthreads();          // stage(t+1) complete
    LOADV(t + 1, vqaA, vqbA);
    if (t + 2 < 16) stage(t + 2);
    MFMA_INTO(accA, t + 1);   // tile t+1
    UPDATE(accB, vqaB, vqbB); // tile t
  }

  // ---- epilogue: tile 15 ----
  __syncthreads();            // stage(15) complete
  LOADV(15, vqaB, vqbB);
  MFMA_INTO(accB, 15);        // tile 15
  UPDATE(accA, vqaA, vqbA);   // tile 14
  UPDATE(accB, vqaB, vqbB);   // tile 15

#undef LOADV
#undef MFMA_INTO
#undef UPDATE

  // ---- merge across the 32 sk-lanes (kh preserved; e-sets disjoint) ----
#pragma unroll
  for (int mask = 1; mask <= 16; mask <<= 1) {
#pragma unroll
    for (int s = 0; s < 16; ++s) {
      mst[s] = fmaxf(mst[s], __shfl_xor(mst[s], mask));
      sst[s] += __shfl_xor(sst[s], mask);
      vst[s] += __shfl_xor(vst[s], mask);
    }
  }

  if (l31 == 0) {
    float* orow = vsum + (size_t)(b * SS + sq) * DD;
#pragma unroll
    for (int grp = 0; grp < 4; ++grp) {
      f32x4 o;
#pragma unroll
      for (int j = 0; j < 4; ++j) {
        const int s = grp * 4 + j;
        const float tt = LN2 * __builtin_amdgcn_exp2f(-mst[s]);
        o[j] = vst[s] * tt / (sst[s] * tt + 1.0f);
      }
      *(f32x4*)(orow + sbase + 8 * grp + 4 * kh) = o;
    }
  }
}

// ------------------------------------------------------------------
extern "C" void kernel_launch(void* const* d_in, const int* in_sizes, int n_in,
                              void* d_out, int out_size, void* d_ws, size_t ws_size,
                              hipStream_t stream) {
  const float* x     = (const float*)d_in[0];
  const float* w_pre = (const float*)d_in[1];
  const float* w_q   = (const float*)d_in[2];
  const float* w_k   = (const float*)d_in[3];
  const float* w_va  = (const float*)d_in[4];
  const float* w_al  = (const float*)d_in[5];
  const float* w_vo  = (const float*)d_in[6];
  const float* w_end = (const float*)d_in[7];
  float* out = (float*)d_out;

  char* ws = (char*)d_ws;
  float*    X     = (float*)(ws);                         // 1MB
  float*    Y     = (float*)(ws + (1 << 20));             // 1MB
  float*    vsum  = (float*)(ws + (2 << 20));             // 1MB
  _Float16* qf16  = (_Float16*)(ws + (3 << 20));          // 512KB
  _Float16* kf16  = (_Float16*)(ws + (3 << 20) + (512 << 10));
  _Float16* vf16  = (_Float16*)(ws + (4 << 20));
  _Float16* kfrag = (_Float16*)(ws + (4 << 20) + (512 << 10));  // 512KB
  _Float16* vfrag = (_Float16*)(ws + (5 << 20));                // 512KB
  unsigned short* wbf = (unsigned short*)(ws + (5 << 20) + (512 << 10));
  // wbf order: pre, q, k, va, vo, end, walI(+I, f16)

  prep_weights<<<224, 256, 0, stream>>>(w_pre, w_q, w_k, w_va, w_vo, w_end,
                                        w_al, wbf);
  linear_bf<<<256, 256, 0, stream>>>(x, wbf + 0 * 65536, nullptr, nullptr, X);
  linear_qkv<<<256, 256, 0, stream>>>(X, wbf + 1 * 65536, wbf + 2 * 65536,
                                      wbf + 3 * 65536, qf16, kf16, vf16);
  pack_kv<<<256, 256, 0, stream>>>(kf16, vf16, kfrag, vfrag);
  fractal_attn<<<2048, 256, 0, stream>>>((const _Float16*)(wbf + 6 * 65536),
                                         qf16, kfrag, vfrag, vsum);
  linear_bf<<<256, 256, 0, stream>>>(vsum, wbf + 4 * 65536, vsum, X, Y);
  linear_bf<<<256, 256, 0, stream>>>(Y, wbf + 5 * 65536, nullptr, nullptr, out);
}

// Round 14
// 257.226 us; speedup vs baseline: 2.4112x; 2.4112x over previous
//
#include <hip/hip_runtime.h>
#include <hip/hip_bf16.h>

// FractalTransformer fused kernels, round 14 (= r13 with the spill fixed).
// r13's 32x32x16 kernel was CORRECT (absmax 0.0039) but launch_bounds(256,3)
// gave a 168-reg budget for a ~175-reg live set -> accumulator spill every
// tile (FETCH 1.34GB, 613us). Fix: launch_bounds(256,2) (256-reg class).
// Occupancy drops to 2 waves/SIMD, but r6-vs-r11 showed occupancy 2->3 was
// only ~4%; spill-free 32x32 (-17% MFMA cyc) + halved tiles/barriers is
// the bigger term. Everything else identical to r13.

typedef __attribute__((ext_vector_type(8))) short short8;
typedef __attribute__((ext_vector_type(4))) float f32x4;
typedef __attribute__((ext_vector_type(16))) float f32x16;
typedef __attribute__((ext_vector_type(8))) _Float16 half8;
typedef __attribute__((ext_vector_type(4))) _Float16 half4;

#define DD 256
#define SS 512
#define LOG2E 1.4426950408889634f
#define LN2   0.6931471805599453f

__device__ __forceinline__ unsigned short f2bf(float f) {
  unsigned int b = __float_as_uint(f);
  b += 0x7FFFu + ((b >> 16) & 1u);   // RNE
  return (unsigned short)(b >> 16);
}
__device__ __forceinline__ short8 cvt8(f32x4 lo, f32x4 hi) {
  short8 r;
  r[0]=(short)f2bf(lo[0]); r[1]=(short)f2bf(lo[1]);
  r[2]=(short)f2bf(lo[2]); r[3]=(short)f2bf(lo[3]);
  r[4]=(short)f2bf(hi[0]); r[5]=(short)f2bf(hi[1]);
  r[6]=(short)f2bf(hi[2]); r[7]=(short)f2bf(hi[3]);
  return r;
}
__device__ __forceinline__ void gload16(const void* g, void* l) {
  __builtin_amdgcn_global_load_lds(
      (const __attribute__((address_space(1))) void*)g,
      (__attribute__((address_space(3))) void*)l,
      16, 0, 0);
}

// ------------------------------------------------------------------
// One-time: bf16-convert 6 weights; (w_al + I) -> f16. out = 7 x [256][256].
// ------------------------------------------------------------------
__global__ __launch_bounds__(256) void prep_weights(
    const float* __restrict__ w0, const float* __restrict__ w1,
    const float* __restrict__ w2, const float* __restrict__ w3,
    const float* __restrict__ w4, const float* __restrict__ w5,
    const float* __restrict__ wal, unsigned short* __restrict__ out)
{
  const int bi = blockIdx.x;               // 7*32
  const int m = bi >> 5;
  const int off = ((bi & 31) * 256 + threadIdx.x) * 8;
  const float* src = m==0?w0: m==1?w1: m==2?w2: m==3?w3: m==4?w4: m==5?w5: wal;
  f32x4 a = *(const f32x4*)(src + off);
  f32x4 b = *(const f32x4*)(src + off + 4);
  if (m == 6) {                            // fold residual (+I), store f16
    const int e = off >> 8, d = off & 255;
#pragma unroll
    for (int jj = 0; jj < 4; ++jj) {
      if (e == d + jj)     a[jj] += 1.0f;
      if (e == d + 4 + jj) b[jj] += 1.0f;
    }
    half8 h;
#pragma unroll
    for (int jj = 0; jj < 4; ++jj) {
      h[jj]     = (_Float16)a[jj];
      h[jj + 4] = (_Float16)b[jj];
    }
    *(half8*)(out + (size_t)m * 65536 + off) = h;
  } else {
    *(short8*)(out + (size_t)m * 65536 + off) = cvt8(a, b);
  }
}

// ------------------------------------------------------------------
// out[1024,256] = A @ Wbf^T (+res1)(+res2). grid 256 = 64 rowblk x 4 colblk.
// ------------------------------------------------------------------
__global__ __launch_bounds__(256) void linear_bf(
    const float* __restrict__ A, const unsigned short* __restrict__ Wbf,
    const float* __restrict__ res1, const float* __restrict__ res2,
    float* __restrict__ out)
{
  const int bi = blockIdx.x;
  const int rb = (bi >> 2) * 16;
  const int cb = (bi & 3) * 64;
  const int tid = threadIdx.x;
  const int wv = tid >> 6, lane = tid & 63;
  const int g = lane >> 4, c = lane & 15;
  const int arow = rb + c;
  const int wrow = cb + wv * 16 + c;

  f32x4 acc = (f32x4){0.f, 0.f, 0.f, 0.f};
#pragma unroll
  for (int ks = 0; ks < 8; ++ks) {
    const int d0 = ks * 32 + g * 8;
    f32x4 a0 = *(const f32x4*)(A + arow * DD + d0);
    f32x4 a1 = *(const f32x4*)(A + arow * DD + d0 + 4);
    short8 av = cvt8(a0, a1);
    short8 bv = *(const short8*)(Wbf + wrow * DD + d0);
    acc = __builtin_amdgcn_mfma_f32_16x16x32_bf16(av, bv, acc, 0, 0, 0);
  }
#pragma unroll
  for (int j = 0; j < 4; ++j) {
    const int ro = rb + g * 4 + j;
    const int co = cb + wv * 16 + c;
    float v = acc[j];
    if (res1) v += res1[ro * DD + co];
    if (res2) v += res2[ro * DD + co];
    out[ro * DD + co] = v;
  }
}

// ------------------------------------------------------------------
// q = f16((X + X@Wq^T)*log2e);  k,v = f16(X + X@{Wk,Wv}^T)
// ------------------------------------------------------------------
__global__ __launch_bounds__(256) void linear_qkv(
    const float* __restrict__ X,
    const unsigned short* __restrict__ Wq, const unsigned short* __restrict__ Wk,
    const unsigned short* __restrict__ Wv,
    _Float16* __restrict__ qout, _Float16* __restrict__ kout,
    _Float16* __restrict__ vout)
{
  const int bi = blockIdx.x;
  const int rb = (bi >> 2) * 16;
  const int cb = (bi & 3) * 64;
  const int tid = threadIdx.x;
  const int wv = tid >> 6, lane = tid & 63;
  const int g = lane >> 4, c = lane & 15;
  const int arow = rb + c;
  const int wrow = cb + wv * 16 + c;

  f32x4 aq = (f32x4){0.f,0.f,0.f,0.f};
  f32x4 ak = (f32x4){0.f,0.f,0.f,0.f};
  f32x4 av_ = (f32x4){0.f,0.f,0.f,0.f};
#pragma unroll
  for (int ks = 0; ks < 8; ++ks) {
    const int d0 = ks * 32 + g * 8;
    f32x4 a0 = *(const f32x4*)(X + arow * DD + d0);
    f32x4 a1 = *(const f32x4*)(X + arow * DD + d0 + 4);
    short8 af = cvt8(a0, a1);
    short8 bq = *(const short8*)(Wq + wrow * DD + d0);
    aq = __builtin_amdgcn_mfma_f32_16x16x32_bf16(af, bq, aq, 0, 0, 0);
    short8 bk = *(const short8*)(Wk + wrow * DD + d0);
    ak = __builtin_amdgcn_mfma_f32_16x16x32_bf16(af, bk, ak, 0, 0, 0);
    short8 bv = *(const short8*)(Wv + wrow * DD + d0);
    av_ = __builtin_amdgcn_mfma_f32_16x16x32_bf16(af, bv, av_, 0, 0, 0);
  }
#pragma unroll
  for (int j = 0; j < 4; ++j) {
    const int ro = rb + g * 4 + j;
    const int co = cb + wv * 16 + c;
    const float base = X[ro * DD + co];
    qout[ro * DD + co] = (_Float16)((base + aq[j]) * LOG2E);
    kout[ro * DD + co] = (_Float16)(base + ak[j]);
    vout[ro * DD + co] = (_Float16)(base + av_[j]);
  }
}

// ------------------------------------------------------------------
// Pack k,v (f16, [b][s][d]) into 32x32x16 fragment order.
// k (ids 0..32767): id = b*16384 + t*1024 + ks*64 + lane -> 8 f16:
//   k[b][t*32 + (lane&31)][ks*16 + (lane>>5)*8 + 0..7]
// v (ids 32768..65535): id2 = b*16384 + t*1024 + slice*128 + lane*2 + g2
//   -> 8 f16: v[b][t*32 + (lane&31)][eb + {0..3, 8..11}],
//   eb = slice*32 + 4*(lane>>5) + 16*g2
// ------------------------------------------------------------------
__global__ __launch_bounds__(256) void pack_kv(
    const _Float16* __restrict__ k, const _Float16* __restrict__ v,
    _Float16* __restrict__ kfrag, _Float16* __restrict__ vfrag)
{
  const int id = blockIdx.x * 256 + threadIdx.x;   // 65536
  if (id < 32768) {
    const int lane = id & 63, ks = (id >> 6) & 15, t = (id >> 10) & 15, b = id >> 14;
    const _Float16* src = k + ((size_t)(b * SS + t * 32 + (lane & 31)) * DD
                               + ks * 16 + (lane >> 5) * 8);
    *(half8*)(kfrag + (size_t)id * 8) = *(const half8*)src;
  } else {
    const int id2 = id - 32768;                    // 0..32767
    const int g2 = id2 & 1, lane = (id2 >> 1) & 63, slice = (id2 >> 7) & 7,
              t = (id2 >> 10) & 15, b = id2 >> 14;
    const int row = b * SS + t * 32 + (lane & 31);
    const int eb = slice * 32 + 4 * (lane >> 5) + 16 * g2;
    half4 lo = *(const half4*)(v + (size_t)row * DD + eb);
    half4 hi = *(const half4*)(v + (size_t)row * DD + eb + 8);
    half8 h;
#pragma unroll
    for (int j = 0; j < 4; ++j) { h[j] = lo[j]; h[j + 4] = hi[j]; }
    *(half8*)(vfrag + (size_t)id2 * 8) = h;
  }
}

// ------------------------------------------------------------------
// Fused fractal attention v14. Grid 2048 = b x sq x eh; 4 waves (256 thr).
// slice = eh*4+wv owns e in [slice*32, +32). 16 tiles of 32 sk;
// mfma_f32_32x32x16_f16 (16 MFMAs/tile). k tiles (16KB fragment-linear)
// LDS double-buffered via straight gload_lds; T15 accA/accB pipeline;
// 1 __syncthreads per tile. launch_bounds(256,2): 256-reg class, NO spill.
// ------------------------------------------------------------------
__global__ __launch_bounds__(256, 2) void fractal_attn(
    const _Float16* __restrict__ walI,   // f16 (wal+I), [256][256]
    const _Float16* __restrict__ qf,     // f16, pre-scaled by log2e
    const _Float16* __restrict__ kfrag,  // f16 fragment-packed (32x32x16)
    const _Float16* __restrict__ vfrag,  // f16 fragment-packed (slice-32)
    float* __restrict__ vsum)
{
  __shared__ _Float16 kt[2][8192];       // 2 x 16KB k tiles

  const int bid = blockIdx.x;            // 2048
  const int eh = bid & 1;
  const int sq = (bid >> 1) & 511;
  const int b  = bid >> 10;
  const int tid = threadIdx.x;
  const int wv = tid >> 6;
  const int lane = tid & 63;
  const int l31 = lane & 31, kh = lane >> 5;
  const int slice = eh * 4 + wv;
  const int sbase = slice * 32;

  // ---- k tile staging: straight linear copy, 256 thr x 4 x 16B = 16KB ----
  const _Float16* ktile0 = kfrag + (size_t)b * 131072;   // + t*8192 halfs
  auto stage = [&](int t) {
    const _Float16* src = ktile0 + (size_t)t * 8192;
    _Float16* dst = &kt[t & 1][0];
#pragma unroll
    for (int it = 0; it < 4; ++it)
      gload16(src + it * 2048 + tid * 8, dst + it * 2048 + tid * 8);
  };

  stage(0);   // completes while we build A'

  // ---- A' fragments: lane holds e = sbase + l31, k-half kh ----
  half8 afrag[16];
  {
    const _Float16* qrow = qf + (size_t)(b * SS + sq) * DD;
    const _Float16* wrow = walI + (size_t)(sbase + l31) * DD;
#pragma unroll
    for (int ks = 0; ks < 16; ++ks) {
      half8 q8 = *(const half8*)(qrow + ks * 16 + kh * 8);
      half8 w8 = *(const half8*)(wrow + ks * 16 + kh * 8);
      afrag[ks] = w8 * q8;
    }
  }

  // ---- v fragment base: half off = b*131072 + t*8192 + slice*1024 + lane*16
  const _Float16* vfb = vfrag + (size_t)b * 131072 + slice * 1024 + lane * 16;

  // ---- state: 16 e-slots per lane; e = sbase+(s&3)+8*(s>>2)+4*kh ----
  float mst[16], sst[16], vst[16];
#pragma unroll
  for (int s = 0; s < 16; ++s) { mst[s] = -1e30f; sst[s] = 0.f; vst[s] = 0.f; }

  f32x16 accA, accB;
  half8 vqaA, vqbA, vqaB, vqbB;
  const f32x16 zeroc = (f32x16)(0.f);

#define LOADV(T, A_, B_)                                            \
  {                                                                 \
    const _Float16* vf_ = vfb + (size_t)(T) * 8192;                 \
    A_ = *(const half8*)(vf_);                                      \
    B_ = *(const half8*)(vf_ + 8);                                  \
  }
#define MFMA_INTO(ACC, T)                                           \
  {                                                                 \
    const _Float16* kb_ = &kt[(T) & 1][0];                          \
    __builtin_amdgcn_s_setprio(1);                                  \
    {                                                               \
      half8 bf0 = *(const half8*)(kb_ + lane * 8);                  \
      ACC = __builtin_amdgcn_mfma_f32_32x32x16_f16(                 \
          afrag[0], bf0, zeroc, 0, 0, 0);                           \
    }                                                               \
    _Pragma("unroll")                                               \
    for (int ks = 1; ks < 16; ++ks) {                               \
      half8 bf_ = *(const half8*)(kb_ + ks * 512 + lane * 8);       \
      ACC = __builtin_amdgcn_mfma_f32_32x32x16_f16(                 \
          afrag[ks], bf_, ACC, 0, 0, 0);                            \
    }                                                               \
    __builtin_amdgcn_s_setprio(0);                                  \
  }
#define UPDATE(ACC, VA, VB)                                         \
  {                                                                 \
    _Pragma("unroll")                                               \
    for (int s = 0; s < 16; ++s) {                                  \
      const float L = ACC[s];                                       \
      mst[s] = fmaxf(mst[s], L);                                    \
      const float p = L * __builtin_amdgcn_exp2f(L);                \
      sst[s] += fabsf(p);                                           \
      const float vv = (s < 8) ? (float)VA[s] : (float)VB[s - 8];   \
      vst[s] = fmaf(vv, p, vst[s]);                                 \
    }                                                               \
  }

  // ---- prologue ----
  LOADV(0, vqaA, vqbA);
  __syncthreads();            // stage(0) complete
  stage(1);
  MFMA_INTO(accA, 0);         // tile 0

#pragma unroll 1
  for (int t = 1; t < 15; t += 2) {
    __syncthreads();          // stage(t) complete; buf[(t+1)&1] free
    LOADV(t, vqaB, vqbB);
    stage(t + 1);
    MFMA_INTO(accB, t);       // tile t
    UPDATE(accA, vqaA, vqbA); // tile t-1 (overlaps MFMA pipe)

    __syncthreads();          // stage(t+1) complete
    LOADV(t + 1, vqaA, vqbA);
    if (t + 2 < 16) stage(t + 2);
    MFMA_INTO(accA, t + 1);   // tile t+1
    UPDATE(accB, vqaB, vqbB); // tile t
  }

  // ---- epilogue: tile 15 ----
  __syncthreads();            // stage(15) complete
  LOADV(15, vqaB, vqbB);
  MFMA_INTO(accB, 15);        // tile 15
  UPDATE(accA, vqaA, vqbA);   // tile 14
  UPDATE(accB, vqaB, vqbB);   // tile 15

#undef LOADV
#undef MFMA_INTO
#undef UPDATE

  // ---- merge across the 32 sk-lanes (kh preserved; e-sets disjoint) ----
#pragma unroll
  for (int mask = 1; mask <= 16; mask <<= 1) {
#pragma unroll
    for (int s = 0; s < 16; ++s) {
      mst[s] = fmaxf(mst[s], __shfl_xor(mst[s], mask));
      sst[s] += __shfl_xor(sst[s], mask);
      vst[s] += __shfl_xor(vst[s], mask);
    }
  }

  if (l31 == 0) {
    float* orow = vsum + (size_t)(b * SS + sq) * DD;
#pragma unroll
    for (int grp = 0; grp < 4; ++grp) {
      f32x4 o;
#pragma unroll
      for (int j = 0; j < 4; ++j) {
        const int s = grp * 4 + j;
        const float tt = LN2 * __builtin_amdgcn_exp2f(-mst[s]);
        o[j] = vst[s] * tt / (sst[s] * tt + 1.0f);
      }
      *(f32x4*)(orow + sbase + 8 * grp + 4 * kh) = o;
    }
  }
}

// ------------------------------------------------------------------
extern "C" void kernel_launch(void* const* d_in, const int* in_sizes, int n_in,
                              void* d_out, int out_size, void* d_ws, size_t ws_size,
                              hipStream_t stream) {
  const float* x     = (const float*)d_in[0];
  const float* w_pre = (const float*)d_in[1];
  const float* w_q   = (const float*)d_in[2];
  const float* w_k   = (const float*)d_in[3];
  const float* w_va  = (const float*)d_in[4];
  const float* w_al  = (const float*)d_in[5];
  const float* w_vo  = (const float*)d_in[6];
  const float* w_end = (const float*)d_in[7];
  float* out = (float*)d_out;

  char* ws = (char*)d_ws;
  float*    X     = (float*)(ws);                         // 1MB
  float*    Y     = (float*)(ws + (1 << 20));             // 1MB
  float*    vsum  = (float*)(ws + (2 << 20));             // 1MB
  _Float16* qf16  = (_Float16*)(ws + (3 << 20));          // 512KB
  _Float16* kf16  = (_Float16*)(ws + (3 << 20) + (512 << 10));
  _Float16* vf16  = (_Float16*)(ws + (4 << 20));
  _Float16* kfrag = (_Float16*)(ws + (4 << 20) + (512 << 10));  // 512KB
  _Float16* vfrag = (_Float16*)(ws + (5 << 20));                // 512KB
  unsigned short* wbf = (unsigned short*)(ws + (5 << 20) + (512 << 10));
  // wbf order: pre, q, k, va, vo, end, walI(+I, f16)

  prep_weights<<<224, 256, 0, stream>>>(w_pre, w_q, w_k, w_va, w_vo, w_end,
                                        w_al, wbf);
  linear_bf<<<256, 256, 0, stream>>>(x, wbf + 0 * 65536, nullptr, nullptr, X);
  linear_qkv<<<256, 256, 0, stream>>>(X, wbf + 1 * 65536, wbf + 2 * 65536,
                                      wbf + 3 * 65536, qf16, kf16, vf16);
  pack_kv<<<256, 256, 0, stream>>>(kf16, vf16, kfrag, vfrag);
  fractal_attn<<<2048, 256, 0, stream>>>((const _Float16*)(wbf + 6 * 65536),
                                         qf16, kfrag, vfrag, vsum);
  linear_bf<<<256, 256, 0, stream>>>(vsum, wbf + 4 * 65536, vsum, X, Y);
  linear_bf<<<256, 256, 0, stream>>>(Y, wbf + 5 * 65536, nullptr, nullptr, out);
}

// Round 15
// 126.484 us; speedup vs baseline: 4.9035x; 2.0337x over previous
//
#include <hip/hip_runtime.h>
#include <hip/hip_bf16.h>

// FractalTransformer fused kernels, round 15 (corrected).
// Hybrid of the two proven schedules on the 16x16x32 kernel: r11's T15
// two-acc pipeline (UPDATE(t-1) overlaps MFMA(t)) inside r12's 4-deep LDS
// ring with counted vmcnt(6) + raw s_barrier (loads stay in flight across
// barriers; vmcnt(0) only on the last tile). 32 tiles of 16 sk, register
// set identical to r11 (launch_bounds(256,3), no spill).
// Wait audit (3 loads/group): before wait at tile T<30, groups {T,T+1,T+2}
// outstanding (9 loads) -> vmcnt(6) completes group T; T=30 -> vmcnt(3);
// T=31 -> vmcnt(0). Ring reuse distance 4 > prefetch depth 3. vq values
// live in registers one extra tile (consumed by deferred UPDATE) -- safe.

typedef __attribute__((ext_vector_type(8))) short short8;
typedef __attribute__((ext_vector_type(4))) float f32x4;
typedef __attribute__((ext_vector_type(8))) _Float16 half8;
typedef __attribute__((ext_vector_type(4))) _Float16 half4;

#define DD 256
#define SS 512
#define LOG2E 1.4426950408889634f
#define LN2   0.6931471805599453f

__device__ __forceinline__ unsigned short f2bf(float f) {
  unsigned int b = __float_as_uint(f);
  b += 0x7FFFu + ((b >> 16) & 1u);   // RNE
  return (unsigned short)(b >> 16);
}
__device__ __forceinline__ short8 cvt8(f32x4 lo, f32x4 hi) {
  short8 r;
  r[0]=(short)f2bf(lo[0]); r[1]=(short)f2bf(lo[1]);
  r[2]=(short)f2bf(lo[2]); r[3]=(short)f2bf(lo[3]);
  r[4]=(short)f2bf(hi[0]); r[5]=(short)f2bf(hi[1]);
  r[6]=(short)f2bf(hi[2]); r[7]=(short)f2bf(hi[3]);
  return r;
}
__device__ __forceinline__ void gload16(const void* g, void* l) {
  __builtin_amdgcn_global_load_lds(
      (const __attribute__((address_space(1))) void*)g,
      (__attribute__((address_space(3))) void*)l,
      16, 0, 0);
}

// ------------------------------------------------------------------
__global__ __launch_bounds__(256) void prep_weights(
    const float* __restrict__ w0, const float* __restrict__ w1,
    const float* __restrict__ w2, const float* __restrict__ w3,
    const float* __restrict__ w4, const float* __restrict__ w5,
    const float* __restrict__ wal, unsigned short* __restrict__ out)
{
  const int bi = blockIdx.x;               // 7*32
  const int m = bi >> 5;
  const int off = ((bi & 31) * 256 + threadIdx.x) * 8;
  const float* src = m==0?w0: m==1?w1: m==2?w2: m==3?w3: m==4?w4: m==5?w5: wal;
  f32x4 a = *(const f32x4*)(src + off);
  f32x4 b = *(const f32x4*)(src + off + 4);
  if (m == 6) {
    const int e = off >> 8, d = off & 255;
#pragma unroll
    for (int jj = 0; jj < 4; ++jj) {
      if (e == d + jj)     a[jj] += 1.0f;
      if (e == d + 4 + jj) b[jj] += 1.0f;
    }
    half8 h;
#pragma unroll
    for (int jj = 0; jj < 4; ++jj) {
      h[jj]     = (_Float16)a[jj];
      h[jj + 4] = (_Float16)b[jj];
    }
    *(half8*)(out + (size_t)m * 65536 + off) = h;
  } else {
    *(short8*)(out + (size_t)m * 65536 + off) = cvt8(a, b);
  }
}

// ------------------------------------------------------------------
__global__ __launch_bounds__(256) void linear_bf(
    const float* __restrict__ A, const unsigned short* __restrict__ Wbf,
    const float* __restrict__ res1, const float* __restrict__ res2,
    float* __restrict__ out)
{
  const int bi = blockIdx.x;
  const int rb = (bi >> 2) * 16;
  const int cb = (bi & 3) * 64;
  const int tid = threadIdx.x;
  const int wv = tid >> 6, lane = tid & 63;
  const int g = lane >> 4, c = lane & 15;
  const int arow = rb + c;
  const int wrow = cb + wv * 16 + c;

  f32x4 acc = (f32x4){0.f, 0.f, 0.f, 0.f};
#pragma unroll
  for (int ks = 0; ks < 8; ++ks) {
    const int d0 = ks * 32 + g * 8;
    f32x4 a0 = *(const f32x4*)(A + arow * DD + d0);
    f32x4 a1 = *(const f32x4*)(A + arow * DD + d0 + 4);
    short8 av = cvt8(a0, a1);
    short8 bv = *(const short8*)(Wbf + wrow * DD + d0);
    acc = __builtin_amdgcn_mfma_f32_16x16x32_bf16(av, bv, acc, 0, 0, 0);
  }
#pragma unroll
  for (int j = 0; j < 4; ++j) {
    const int ro = rb + g * 4 + j;
    const int co = cb + wv * 16 + c;
    float v = acc[j];
    if (res1) v += res1[ro * DD + co];
    if (res2) v += res2[ro * DD + co];
    out[ro * DD + co] = v;
  }
}

// ------------------------------------------------------------------
__global__ __launch_bounds__(256) void linear_qkv(
    const float* __restrict__ X,
    const unsigned short* __restrict__ Wq, const unsigned short* __restrict__ Wk,
    const unsigned short* __restrict__ Wv,
    _Float16* __restrict__ qout, _Float16* __restrict__ kout,
    _Float16* __restrict__ vout)
{
  const int bi = blockIdx.x;
  const int rb = (bi >> 2) * 16;
  const int cb = (bi & 3) * 64;
  const int tid = threadIdx.x;
  const int wv = tid >> 6, lane = tid & 63;
  const int g = lane >> 4, c = lane & 15;
  const int arow = rb + c;
  const int wrow = cb + wv * 16 + c;

  f32x4 aq = (f32x4){0.f,0.f,0.f,0.f};
  f32x4 ak = (f32x4){0.f,0.f,0.f,0.f};
  f32x4 av_ = (f32x4){0.f,0.f,0.f,0.f};
#pragma unroll
  for (int ks = 0; ks < 8; ++ks) {
    const int d0 = ks * 32 + g * 8;
    f32x4 a0 = *(const f32x4*)(X + arow * DD + d0);
    f32x4 a1 = *(const f32x4*)(X + arow * DD + d0 + 4);
    short8 af = cvt8(a0, a1);
    short8 bq = *(const short8*)(Wq + wrow * DD + d0);
    aq = __builtin_amdgcn_mfma_f32_16x16x32_bf16(af, bq, aq, 0, 0, 0);
    short8 bk = *(const short8*)(Wk + wrow * DD + d0);
    ak = __builtin_amdgcn_mfma_f32_16x16x32_bf16(af, bk, ak, 0, 0, 0);
    short8 bv = *(const short8*)(Wv + wrow * DD + d0);
    av_ = __builtin_amdgcn_mfma_f32_16x16x32_bf16(af, bv, av_, 0, 0, 0);
  }
#pragma unroll
  for (int j = 0; j < 4; ++j) {
    const int ro = rb + g * 4 + j;
    const int co = cb + wv * 16 + c;
    const float base = X[ro * DD + co];
    qout[ro * DD + co] = (_Float16)((base + aq[j]) * LOG2E);
    kout[ro * DD + co] = (_Float16)(base + ak[j]);
    vout[ro * DD + co] = (_Float16)(base + av_[j]);
  }
}

// ------------------------------------------------------------------
// Pack k,v (f16) into fragment order (identical to r11/r12).
// ------------------------------------------------------------------
__global__ __launch_bounds__(256) void pack_kv(
    const _Float16* __restrict__ k, const _Float16* __restrict__ v,
    _Float16* __restrict__ kfrag, _Float16* __restrict__ vfrag)
{
  const int id = blockIdx.x * 256 + threadIdx.x;   // 98304
  if (id < 32768) {
    const int lane = id & 63, ks = (id >> 6) & 7, t2 = (id >> 9) & 31, b = id >> 14;
    const int g = lane >> 4, c = lane & 15;
    const _Float16* src = k + ((size_t)(b * SS + t2 * 16 + c) * DD + ks * 32 + g * 8);
    *(half8*)(kfrag + (size_t)id * 8) = *(const half8*)src;
  } else {
    const int id2 = id - 32768;                    // 0..65535
    const int lane = id2 & 63, i = (id2 >> 6) & 1, slice = (id2 >> 7) & 7,
              t2 = (id2 >> 10) & 31, b = id2 >> 15;
    const int g = lane >> 4, c = lane & 15;
    const _Float16* src = v + ((size_t)(b * SS + t2 * 16 + c) * DD + slice * 32 + i * 16 + g * 4);
    *(half4*)(vfrag + (size_t)id2 * 4) = *(const half4*)src;
  }
}

// ------------------------------------------------------------------
// Fused fractal attention v15. Grid 2048 = b x sq x eh; 4 waves (256 thr).
// 32 tiles of 16 sk. 4-deep LDS ring (48KB), counted vmcnt, one raw
// s_barrier per tile, T15 accA/accB + vqA/vqB pipeline.
// ------------------------------------------------------------------
__global__ __launch_bounds__(256, 3) void fractal_attn(
    const _Float16* __restrict__ walI,
    const _Float16* __restrict__ qf,
    const _Float16* __restrict__ kfrag,
    const _Float16* __restrict__ vfrag,
    float* __restrict__ vsum)
{
  __shared__ _Float16 kt[4][4096];       // 4 x 8KB
  __shared__ _Float16 vt[4][2048];       // 4 x 4KB

  const int bid = blockIdx.x;
  const int eh = bid & 1;
  const int sq = (bid >> 1) & 511;
  const int b  = bid >> 10;
  const int tid = threadIdx.x;
  const int wv = tid >> 6;
  const int lane = tid & 63;
  const int g = lane >> 4, c = lane & 15;
  const int slice = eh * 4 + wv;
  const int sbase = slice * 32;

  const _Float16* ktile0 = kfrag + (size_t)b * 131072;
  const _Float16* vtile0 = vfrag + (size_t)b * 131072 + eh * 2048;
  auto stage = [&](int t) {
    const _Float16* ks = ktile0 + (size_t)t * 4096;
    const _Float16* vs = vtile0 + (size_t)t * 4096;
    _Float16* kd = &kt[t & 3][0];
    _Float16* vd = &vt[t & 3][0];
    gload16(ks + tid * 8,        kd + tid * 8);
    gload16(ks + 2048 + tid * 8, kd + 2048 + tid * 8);
    gload16(vs + tid * 8,        vd + tid * 8);
  };

  stage(0); stage(1); stage(2);

  half8 afrag[2][8];
  {
    const _Float16* qrow = qf + (size_t)(b * SS + sq) * DD;
    half8 q8[8];
#pragma unroll
    for (int ks = 0; ks < 8; ++ks)
      q8[ks] = *(const half8*)(qrow + ks * 32 + g * 8);
#pragma unroll
    for (int i = 0; i < 2; ++i) {
      const int e = sbase + i * 16 + c;
      const _Float16* wrow = walI + (size_t)e * DD;
#pragma unroll
      for (int ks = 0; ks < 8; ++ks)
        afrag[i][ks] = (*(const half8*)(wrow + ks * 32 + g * 8)) * q8[ks];
    }
  }

  float mst[8], sst[8], vst[8];
#pragma unroll
  for (int s = 0; s < 8; ++s) { mst[s] = -1e30f; sst[s] = 0.f; vst[s] = 0.f; }

  half8 bf[8];
  half4 vqA[2], vqB[2];
  f32x4 accA[2], accB[2];
  const f32x4 zeroc = (f32x4){0.f, 0.f, 0.f, 0.f};

#define DSREAD(T)                                                   \
  {                                                                 \
    const _Float16* kb_ = &kt[(T) & 3][0];                          \
    _Pragma("unroll")                                               \
    for (int ks = 0; ks < 8; ++ks)                                  \
      bf[ks] = *(const half8*)(kb_ + ks * 512 + lane * 8);          \
  }
#define DSVREAD(T, VQ)                                              \
  {                                                                 \
    const _Float16* vb_ = &vt[(T) & 3][0];                          \
    VQ[0] = *(const half4*)(vb_ + wv * 512 + lane * 4);             \
    VQ[1] = *(const half4*)(vb_ + wv * 512 + 256 + lane * 4);       \
  }
#define MFMA_INTO(ACC)                                              \
  {                                                                 \
    __builtin_amdgcn_s_setprio(1);                                  \
    ACC[0] = __builtin_amdgcn_mfma_f32_16x16x32_f16(                \
        afrag[0][0], bf[0], zeroc, 0, 0, 0);                        \
    ACC[1] = __builtin_amdgcn_mfma_f32_16x16x32_f16(                \
        afrag[1][0], bf[0], zeroc, 0, 0, 0);                        \
    _Pragma("unroll")                                               \
    for (int ks = 1; ks < 8; ++ks) {                                \
      ACC[0] = __builtin_amdgcn_mfma_f32_16x16x32_f16(              \
          afrag[0][ks], bf[ks], ACC[0], 0, 0, 0);                   \
      ACC[1] = __builtin_amdgcn_mfma_f32_16x16x32_f16(              \
          afrag[1][ks], bf[ks], ACC[1], 0, 0, 0);                   \
    }                                                               \
    __builtin_amdgcn_s_setprio(0);                                  \
  }
#define UPDATE(ACC, VQ)                                             \
  {                                                                 \
    _Pragma("unroll")                                               \
    for (int i = 0; i < 2; ++i)                                     \
      _Pragma("unroll")                                             \
      for (int j = 0; j < 4; ++j) {                                 \
        const int s = i * 4 + j;                                    \
        const float L = ACC[i][j];                                  \
        mst[s] = fmaxf(mst[s], L);                                  \
        const float p = L * __builtin_amdgcn_exp2f(L);              \
        sst[s] += fabsf(p);                                         \
        vst[s] = fmaf((float)VQ[i][j], p, vst[s]);                  \
      }                                                             \
  }
#define WAIT(N) asm volatile("s_waitcnt vmcnt(" #N ")" ::: "memory")

  // ---- tile 0 (accA) ----
  WAIT(6); __builtin_amdgcn_s_barrier();
  stage(3);
  DSREAD(0); DSVREAD(0, vqA);
  MFMA_INTO(accA);

  // ---- pairs (t, t+1), t = 1,3,...,27 ----
#pragma unroll 1
  for (int t = 1; t < 29; t += 2) {
    WAIT(6); __builtin_amdgcn_s_barrier();
    stage(t + 3);
    DSREAD(t); DSVREAD(t, vqB);
    MFMA_INTO(accB);
    UPDATE(accA, vqA);

    WAIT(6); __builtin_amdgcn_s_barrier();
    if (t + 4 < 32) stage(t + 4);
    DSREAD(t + 1); DSVREAD(t + 1, vqA);
    MFMA_INTO(accA);
    UPDATE(accB, vqB);
  }

  // ---- tile 29 (accB): groups 29,30,31 outstanding -> wait 6 ----
  WAIT(6); __builtin_amdgcn_s_barrier();
  DSREAD(29); DSVREAD(29, vqB);
  MFMA_INTO(accB);
  UPDATE(accA, vqA);

  // ---- tile 30 (accA): groups 30,31 -> wait 3 ----
  WAIT(3); __builtin_amdgcn_s_barrier();
  DSREAD(30); DSVREAD(30, vqA);
  MFMA_INTO(accA);
  UPDATE(accB, vqB);

  // ---- tile 31 (accB): group 31 -> wait 0 ----
  WAIT(0); __builtin_amdgcn_s_barrier();
  DSREAD(31); DSVREAD(31, vqB);
  MFMA_INTO(accB);
  UPDATE(accA, vqA);
  UPDATE(accB, vqB);

#undef DSREAD
#undef DSVREAD
#undef MFMA_INTO
#undef UPDATE
#undef WAIT

#pragma unroll
  for (int mask = 1; mask <= 8; mask <<= 1) {
#pragma unroll
    for (int s = 0; s < 8; ++s) {
      mst[s] = fmaxf(mst[s], __shfl_xor(mst[s], mask));
      sst[s] += __shfl_xor(sst[s], mask);
      vst[s] += __shfl_xor(vst[s], mask);
    }
  }

  if (c == 0) {
    float* orow = vsum + (size_t)(b * SS + sq) * DD;
#pragma unroll
    for (int i = 0; i < 2; ++i) {
      f32x4 o;
#pragma unroll
      for (int j = 0; j < 4; ++j) {
        const int s = i * 4 + j;
        const float tt = LN2 * __builtin_amdgcn_exp2f(-mst[s]);
        o[j] = vst[s] * tt / (sst[s] * tt + 1.0f);
      }
      *(f32x4*)(orow + sbase + i * 16 + g * 4) = o;
    }
  }
}

// ------------------------------------------------------------------
extern "C" void kernel_launch(void* const* d_in, const int* in_sizes, int n_in,
                              void* d_out, int out_size, void* d_ws, size_t ws_size,
                              hipStream_t stream) {
  const float* x     = (const float*)d_in[0];
  const float* w_pre = (const float*)d_in[1];
  const float* w_q   = (const float*)d_in[2];
  const float* w_k   = (const float*)d_in[3];
  const float* w_va  = (const float*)d_in[4];
  const float* w_al  = (const float*)d_in[5];
  const float* w_vo  = (const float*)d_in[6];
  const float* w_end = (const float*)d_in[7];
  float* out = (float*)d_out;

  char* ws = (char*)d_ws;
  float*    X     = (float*)(ws);
  float*    Y     = (float*)(ws + (1 << 20));
  float*    vsum  = (float*)(ws + (2 << 20));
  _Float16* qf16  = (_Float16*)(ws + (3 << 20));
  _Float16* kf16  = (_Float16*)(ws + (3 << 20) + (512 << 10));
  _Float16* vf16  = (_Float16*)(ws + (4 << 20));
  _Float16* kfrag = (_Float16*)(ws + (4 << 20) + (512 << 10));
  _Float16* vfrag = (_Float16*)(ws + (5 << 20));
  unsigned short* wbf = (unsigned short*)(ws + (5 << 20) + (512 << 10));

  prep_weights<<<224, 256, 0, stream>>>(w_pre, w_q, w_k, w_va, w_vo, w_end,
                                        w_al, wbf);
  linear_bf<<<256, 256, 0, stream>>>(x, wbf + 0 * 65536, nullptr, nullptr, X);
  linear_qkv<<<256, 256, 0, stream>>>(X, wbf + 1 * 65536, wbf + 2 * 65536,
                                      wbf + 3 * 65536, qf16, kf16, vf16);
  pack_kv<<<384, 256, 0, stream>>>(kf16, vf16, kfrag, vfrag);
  fractal_attn<<<2048, 256, 0, stream>>>((const _Float16*)(wbf + 6 * 65536),
                                         qf16, kfrag, vfrag, vsum);
  linear_bf<<<256, 256, 0, stream>>>(vsum, wbf + 4 * 65536, vsum, X, Y);
  linear_bf<<<256, 256, 0, stream>>>(Y, wbf + 5 * 65536, nullptr, nullptr, out);
}

// Round 16
// 118.102 us; speedup vs baseline: 5.2515x; 1.0710x over previous
//
#include <hip/hip_runtime.h>
#include <hip/hip_bf16.h>

// FractalTransformer fused kernels, round 16.
// r12-r15 all failed to beat r11's attn (98.2us): counted-vmcnt, deeper
// rings, 32x32 shape, occupancy forcing -- each regressed or spilled.
// Verdict: r11 is the schedule plateau. This round: (1) fractal_attn
// reverted to r11 VERBATIM; (2) pack_kv fused into linear_qkv (k/v tiles
// transposed through a 4KB LDS buffer and written fragment-packed
// directly) -- one fewer dispatch and 2MB less L2 round-trip.

typedef __attribute__((ext_vector_type(8))) short short8;
typedef __attribute__((ext_vector_type(4))) float f32x4;
typedef __attribute__((ext_vector_type(8))) _Float16 half8;
typedef __attribute__((ext_vector_type(4))) _Float16 half4;

#define DD 256
#define SS 512
#define LOG2E 1.4426950408889634f
#define LN2   0.6931471805599453f

__device__ __forceinline__ unsigned short f2bf(float f) {
  unsigned int b = __float_as_uint(f);
  b += 0x7FFFu + ((b >> 16) & 1u);   // RNE
  return (unsigned short)(b >> 16);
}
__device__ __forceinline__ short8 cvt8(f32x4 lo, f32x4 hi) {
  short8 r;
  r[0]=(short)f2bf(lo[0]); r[1]=(short)f2bf(lo[1]);
  r[2]=(short)f2bf(lo[2]); r[3]=(short)f2bf(lo[3]);
  r[4]=(short)f2bf(hi[0]); r[5]=(short)f2bf(hi[1]);
  r[6]=(short)f2bf(hi[2]); r[7]=(short)f2bf(hi[3]);
  return r;
}
__device__ __forceinline__ void gload16(const void* g, void* l) {
  __builtin_amdgcn_global_load_lds(
      (const __attribute__((address_space(1))) void*)g,
      (__attribute__((address_space(3))) void*)l,
      16, 0, 0);
}

// ------------------------------------------------------------------
// One-time: bf16-convert 6 weights; (w_al + I) -> f16. out = 7 x [256][256].
// ------------------------------------------------------------------
__global__ __launch_bounds__(256) void prep_weights(
    const float* __restrict__ w0, const float* __restrict__ w1,
    const float* __restrict__ w2, const float* __restrict__ w3,
    const float* __restrict__ w4, const float* __restrict__ w5,
    const float* __restrict__ wal, unsigned short* __restrict__ out)
{
  const int bi = blockIdx.x;               // 7*32
  const int m = bi >> 5;
  const int off = ((bi & 31) * 256 + threadIdx.x) * 8;
  const float* src = m==0?w0: m==1?w1: m==2?w2: m==3?w3: m==4?w4: m==5?w5: wal;
  f32x4 a = *(const f32x4*)(src + off);
  f32x4 b = *(const f32x4*)(src + off + 4);
  if (m == 6) {                            // fold residual (+I), store f16
    const int e = off >> 8, d = off & 255;
#pragma unroll
    for (int jj = 0; jj < 4; ++jj) {
      if (e == d + jj)     a[jj] += 1.0f;
      if (e == d + 4 + jj) b[jj] += 1.0f;
    }
    half8 h;
#pragma unroll
    for (int jj = 0; jj < 4; ++jj) {
      h[jj]     = (_Float16)a[jj];
      h[jj + 4] = (_Float16)b[jj];
    }
    *(half8*)(out + (size_t)m * 65536 + off) = h;
  } else {
    *(short8*)(out + (size_t)m * 65536 + off) = cvt8(a, b);
  }
}

// ------------------------------------------------------------------
// out[1024,256] = A @ Wbf^T (+res1)(+res2). grid 256 = 64 rowblk x 4 colblk.
// ------------------------------------------------------------------
__global__ __launch_bounds__(256) void linear_bf(
    const float* __restrict__ A, const unsigned short* __restrict__ Wbf,
    const float* __restrict__ res1, const float* __restrict__ res2,
    float* __restrict__ out)
{
  const int bi = blockIdx.x;
  const int rb = (bi >> 2) * 16;
  const int cb = (bi & 3) * 64;
  const int tid = threadIdx.x;
  const int wv = tid >> 6, lane = tid & 63;
  const int g = lane >> 4, c = lane & 15;
  const int arow = rb + c;
  const int wrow = cb + wv * 16 + c;

  f32x4 acc = (f32x4){0.f, 0.f, 0.f, 0.f};
#pragma unroll
  for (int ks = 0; ks < 8; ++ks) {
    const int d0 = ks * 32 + g * 8;
    f32x4 a0 = *(const f32x4*)(A + arow * DD + d0);
    f32x4 a1 = *(const f32x4*)(A + arow * DD + d0 + 4);
    short8 av = cvt8(a0, a1);
    short8 bv = *(const short8*)(Wbf + wrow * DD + d0);
    acc = __builtin_amdgcn_mfma_f32_16x16x32_bf16(av, bv, acc, 0, 0, 0);
  }
#pragma unroll
  for (int j = 0; j < 4; ++j) {
    const int ro = rb + g * 4 + j;
    const int co = cb + wv * 16 + c;
    float v = acc[j];
    if (res1) v += res1[ro * DD + co];
    if (res2) v += res2[ro * DD + co];
    out[ro * DD + co] = v;
  }
}

// ------------------------------------------------------------------
// q = f16((X + X@Wq^T)*log2e);  k,v = f16(X + X@{Wk,Wv}^T), written
// DIRECTLY in fragment-packed order via an LDS transpose (pack_kv fused).
// Block (rb,cb): rb = 16-row strip (t2 = (rb>>4)&31, b = rb>>9),
// cb = 64-col strip (ks/slice base = cb>>5, covers 2 of 8).
// ------------------------------------------------------------------
__global__ __launch_bounds__(256) void linear_qkv(
    const float* __restrict__ X,
    const unsigned short* __restrict__ Wq, const unsigned short* __restrict__ Wk,
    const unsigned short* __restrict__ Wv,
    _Float16* __restrict__ qout,
    _Float16* __restrict__ kfrag, _Float16* __restrict__ vfrag)
{
  __shared__ _Float16 kl[16][64];
  __shared__ _Float16 vl[16][64];

  const int bi = blockIdx.x;
  const int rb = (bi >> 2) * 16;
  const int cb = (bi & 3) * 64;
  const int tid = threadIdx.x;
  const int wv = tid >> 6, lane = tid & 63;
  const int g = lane >> 4, c = lane & 15;
  const int arow = rb + c;
  const int wrow = cb + wv * 16 + c;

  f32x4 aq = (f32x4){0.f,0.f,0.f,0.f};
  f32x4 ak = (f32x4){0.f,0.f,0.f,0.f};
  f32x4 av_ = (f32x4){0.f,0.f,0.f,0.f};
#pragma unroll
  for (int ks = 0; ks < 8; ++ks) {
    const int d0 = ks * 32 + g * 8;
    f32x4 a0 = *(const f32x4*)(X + arow * DD + d0);
    f32x4 a1 = *(const f32x4*)(X + arow * DD + d0 + 4);
    short8 af = cvt8(a0, a1);
    short8 bq = *(const short8*)(Wq + wrow * DD + d0);
    aq = __builtin_amdgcn_mfma_f32_16x16x32_bf16(af, bq, aq, 0, 0, 0);
    short8 bk = *(const short8*)(Wk + wrow * DD + d0);
    ak = __builtin_amdgcn_mfma_f32_16x16x32_bf16(af, bk, ak, 0, 0, 0);
    short8 bv = *(const short8*)(Wv + wrow * DD + d0);
    av_ = __builtin_amdgcn_mfma_f32_16x16x32_bf16(af, bv, av_, 0, 0, 0);
  }
#pragma unroll
  for (int j = 0; j < 4; ++j) {
    const int ro = rb + g * 4 + j;
    const int co = cb + wv * 16 + c;
    const float base = X[ro * DD + co];
    qout[ro * DD + co] = (_Float16)((base + aq[j]) * LOG2E);
    kl[g * 4 + j][wv * 16 + c] = (_Float16)(base + ak[j]);
    vl[g * 4 + j][wv * 16 + c] = (_Float16)(base + av_[j]);
  }
  __syncthreads();

  const int b  = rb >> 9;
  const int t2 = (rb >> 4) & 31;
  const int cg = cb >> 5;                  // ks / slice base (0,2,4,6)

  // k fragment chunks: threads 0..127 -> 2 chunks x 64 lanes x 8 f16
  if (tid < 128) {
    const int ksl = tid >> 6, lane2 = tid & 63;
    const int g2 = lane2 >> 4, c2 = lane2 & 15;
    half8 h = *(const half8*)&kl[c2][ksl * 32 + g2 * 8];
    *(half8*)(kfrag + (size_t)b * 131072 + (size_t)t2 * 4096
              + (cg + ksl) * 512 + lane2 * 8) = h;
  }
  // v fragment chunks: all 256 threads -> 2 slices x 2 i x 64 lanes x 4 f16
  {
    const int sl = tid >> 7, il = (tid >> 6) & 1, lane2 = tid & 63;
    const int g2 = lane2 >> 4, c2 = lane2 & 15;
    half4 h = *(const half4*)&vl[c2][sl * 32 + il * 16 + g2 * 4];
    *(half4*)(vfrag + (size_t)b * 131072 + (size_t)t2 * 4096
              + (cg + sl) * 512 + il * 256 + lane2 * 4) = h;
  }
}

// ------------------------------------------------------------------
// Fused fractal attention — r11 VERBATIM (98.2us proven).
// Grid 2048 = b x sq x eh; 4 waves (256 thr). slice = eh*4+wv owns
// e in [slice*32, +32). k tiles (8KB fragment-linear) staged to LDS
// (double-buffered) via straight global_load_lds; all waves broadcast-
// read conflict-free. T15: accA/accB 2-tile pipeline, UPDATE(t-1) under
// MFMA(t). launch_bounds(256,3).
// ------------------------------------------------------------------
__global__ __launch_bounds__(256, 3) void fractal_attn(
    const _Float16* __restrict__ walI,   // f16 (wal+I), [256][256]
    const _Float16* __restrict__ qf,     // f16, pre-scaled by log2e
    const _Float16* __restrict__ kfrag,  // f16 fragment-packed
    const _Float16* __restrict__ vfrag,  // f16 fragment-packed (slice-32)
    float* __restrict__ vsum)
{
  __shared__ _Float16 kt[2][4096];       // 2 x 8KB k tiles

  const int bid = blockIdx.x;            // 2048
  const int eh = bid & 1;
  const int sq = (bid >> 1) & 511;
  const int b  = bid >> 10;
  const int tid = threadIdx.x;
  const int wv = tid >> 6;
  const int lane = tid & 63;
  const int g = lane >> 4, c = lane & 15;
  const int slice = eh * 4 + wv;
  const int sbase = slice * 32;

  const _Float16* ktile0 = kfrag + (size_t)b * 131072;
  auto stage = [&](int t) {
    const _Float16* src = ktile0 + (size_t)t * 4096;
    _Float16* dst = &kt[t & 1][0];
    gload16(src + tid * 8,        dst + tid * 8);
    gload16(src + 2048 + tid * 8, dst + 2048 + tid * 8);
  };

  stage(0);   // completes while we build A'

  half8 afrag[2][8];
  {
    const _Float16* qrow = qf + (size_t)(b * SS + sq) * DD;
    half8 q8[8];
#pragma unroll
    for (int ks = 0; ks < 8; ++ks)
      q8[ks] = *(const half8*)(qrow + ks * 32 + g * 8);
#pragma unroll
    for (int i = 0; i < 2; ++i) {
      const int e = sbase + i * 16 + c;
      const _Float16* wrow = walI + (size_t)e * DD;
#pragma unroll
      for (int ks = 0; ks < 8; ++ks)
        afrag[i][ks] = (*(const half8*)(wrow + ks * 32 + g * 8)) * q8[ks];
    }
  }

  const _Float16* vfb = vfrag + (size_t)b * 131072 + slice * 512 + lane * 4;

  float mst[8], sst[8], vst[8];
#pragma unroll
  for (int s = 0; s < 8; ++s) { mst[s] = -1e30f; sst[s] = 0.f; vst[s] = 0.f; }

  half8 bf[8];
  half4 vqA[2], vqB[2];
  f32x4 accA[2], accB[2];
  const f32x4 zeroc = (f32x4){0.f, 0.f, 0.f, 0.f};

#define DSREAD(BUF)                                                 \
  {                                                                 \
    const _Float16* kb_ = &kt[BUF][0];                              \
    _Pragma("unroll")                                               \
    for (int ks = 0; ks < 8; ++ks)                                  \
      bf[ks] = *(const half8*)(kb_ + ks * 512 + lane * 8);          \
  }
#define LOADV(T2, VQ)                                               \
  {                                                                 \
    const _Float16* vf_ = vfb + (size_t)(T2) * 4096;                \
    VQ[0] = *(const half4*)(vf_);                                   \
    VQ[1] = *(const half4*)(vf_ + 256);                             \
  }
#define MFMA_INTO(ACC)                                              \
  {                                                                 \
    __builtin_amdgcn_s_setprio(1);                                  \
    ACC[0] = __builtin_amdgcn_mfma_f32_16x16x32_f16(                \
        afrag[0][0], bf[0], zeroc, 0, 0, 0);                        \
    ACC[1] = __builtin_amdgcn_mfma_f32_16x16x32_f16(                \
        afrag[1][0], bf[0], zeroc, 0, 0, 0);                        \
    _Pragma("unroll")                                               \
    for (int ks = 1; ks < 8; ++ks) {                                \
      ACC[0] = __builtin_amdgcn_mfma_f32_16x16x32_f16(              \
          afrag[0][ks], bf[ks], ACC[0], 0, 0, 0);                   \
      ACC[1] = __builtin_amdgcn_mfma_f32_16x16x32_f16(              \
          afrag[1][ks], bf[ks], ACC[1], 0, 0, 0);                   \
    }                                                               \
    __builtin_amdgcn_s_setprio(0);                                  \
  }
#define UPDATE(ACC, VQ)                                             \
  {                                                                 \
    _Pragma("unroll")                                               \
    for (int i = 0; i < 2; ++i)                                     \
      _Pragma("unroll")                                             \
      for (int j = 0; j < 4; ++j) {                                 \
        const int s = i * 4 + j;                                    \
        const float L = ACC[i][j];                                  \
        mst[s] = fmaxf(mst[s], L);                                  \
        const float p = L * __builtin_amdgcn_exp2f(L);              \
        sst[s] += fabsf(p);                                         \
        vst[s] = fmaf((float)VQ[i][j], p, vst[s]);                  \
      }                                                             \
  }

  // ---- prologue ----
  LOADV(0, vqA);
  __syncthreads();            // stage(0) complete
  DSREAD(0);
  stage(1);
  MFMA_INTO(accA);            // tile 0

#pragma unroll 1
  for (int t = 1; t < 31; t += 2) {
    __syncthreads();          // stage(t) complete; buf[(t+1)&1] free
    DSREAD(t & 1);
    LOADV(t, vqB);
    stage(t + 1);
    MFMA_INTO(accB);          // tile t
    UPDATE(accA, vqA);        // tile t-1 (overlaps MFMA pipe)

    __syncthreads();          // stage(t+1) complete
    DSREAD((t + 1) & 1);
    LOADV(t + 1, vqA);
    if (t + 2 < 32) stage(t + 2);
    MFMA_INTO(accA);          // tile t+1
    UPDATE(accB, vqB);        // tile t
  }

  // ---- epilogue: tile 31 ----
  __syncthreads();            // stage(31) complete
  DSREAD(1);
  LOADV(31, vqB);
  MFMA_INTO(accB);            // tile 31
  UPDATE(accA, vqA);          // tile 30
  UPDATE(accB, vqB);          // tile 31

#undef DSREAD
#undef LOADV
#undef MFMA_INTO
#undef UPDATE

#pragma unroll
  for (int mask = 1; mask <= 8; mask <<= 1) {
#pragma unroll
    for (int s = 0; s < 8; ++s) {
      mst[s] = fmaxf(mst[s], __shfl_xor(mst[s], mask));
      sst[s] += __shfl_xor(sst[s], mask);
      vst[s] += __shfl_xor(vst[s], mask);
    }
  }

  if (c == 0) {
    float* orow = vsum + (size_t)(b * SS + sq) * DD;
#pragma unroll
    for (int i = 0; i < 2; ++i) {
      f32x4 o;
#pragma unroll
      for (int j = 0; j < 4; ++j) {
        const int s = i * 4 + j;
        const float tt = LN2 * __builtin_amdgcn_exp2f(-mst[s]);
        o[j] = vst[s] * tt / (sst[s] * tt + 1.0f);
      }
      *(f32x4*)(orow + sbase + i * 16 + g * 4) = o;
    }
  }
}

// ------------------------------------------------------------------
extern "C" void kernel_launch(void* const* d_in, const int* in_sizes, int n_in,
                              void* d_out, int out_size, void* d_ws, size_t ws_size,
                              hipStream_t stream) {
  const float* x     = (const float*)d_in[0];
  const float* w_pre = (const float*)d_in[1];
  const float* w_q   = (const float*)d_in[2];
  const float* w_k   = (const float*)d_in[3];
  const float* w_va  = (const float*)d_in[4];
  const float* w_al  = (const float*)d_in[5];
  const float* w_vo  = (const float*)d_in[6];
  const float* w_end = (const float*)d_in[7];
  float* out = (float*)d_out;

  char* ws = (char*)d_ws;
  float*    X     = (float*)(ws);                          // 1MB
  float*    Y     = (float*)(ws + (1 << 20));              // 1MB
  float*    vsum  = (float*)(ws + (2 << 20));              // 1MB
  _Float16* qf16  = (_Float16*)(ws + (3 << 20));           // 512KB
  _Float16* kfrag = (_Float16*)(ws + (3 << 20) + (512 << 10));  // 512KB
  _Float16* vfrag = (_Float16*)(ws + (4 << 20));           // 512KB
  unsigned short* wbf = (unsigned short*)(ws + (4 << 20) + (512 << 10));
  // wbf order: pre, q, k, va, vo, end, walI(+I, f16)

  prep_weights<<<224, 256, 0, stream>>>(w_pre, w_q, w_k, w_va, w_vo, w_end,
                                        w_al, wbf);
  linear_bf<<<256, 256, 0, stream>>>(x, wbf + 0 * 65536, nullptr, nullptr, X);
  linear_qkv<<<256, 256, 0, stream>>>(X, wbf + 1 * 65536, wbf + 2 * 65536,
                                      wbf + 3 * 65536, qf16, kfrag, vfrag);
  fractal_attn<<<2048, 256, 0, stream>>>((const _Float16*)(wbf + 6 * 65536),
                                         qf16, kfrag, vfrag, vsum);
  linear_bf<<<256, 256, 0, stream>>>(vsum, wbf + 4 * 65536, vsum, X, Y);
  linear_bf<<<256, 256, 0, stream>>>(Y, wbf + 5 * 65536, nullptr, nullptr, out);
}